// Round 7
// baseline (283.711 us; speedup 1.0000x reference)
//
#include <hip/hip_runtime.h>
#include <hip/hip_bf16.h>
#include <hip/hip_cooperative_groups.h>

namespace cg = cooperative_groups;

#define HW 4096
#define CC 64
#define NB 4

typedef short bf16x8 __attribute__((ext_vector_type(8)));
typedef float f32x4 __attribute__((ext_vector_type(4)));

// workspace layout (byte offsets)
#define OFF_F  0                      // bf16 [b][n][8]      262144 B
#define OFF_G  262144                 // bf16 [b][n][8]      262144 B
#define OFF_H  524288                 // bf16 [b][c][n]     2097152 B
#define OFF_ZP 2621440                // f32  [2ich][b][n]   131072 B
#define OFF_O  2752512                // bf16 [2hx][b][c][m] 4194304 B
// end 6946816 (~6.9 MB)

__device__ __forceinline__ float bf2f(short s) {
    unsigned u = ((unsigned)(unsigned short)s) << 16;
    return __uint_as_float(u);
}
__device__ __forceinline__ __hip_bfloat16 f2bf(float f) { return __float2bfloat16(f); }

// ---------------------------------------------------------------------------
// One cooperative kernel, 512 blocks x 256 thr (2 blocks/CU guaranteed:
// LDS 19712 B, launch_bounds(256,2)). Four phases split by grid.sync():
//  P1 conv (MFMA, 32-px tiles) -> fb/gb/hb
//  P2 Z partials (A-frags straight from L2, no big LDS stage) -> zp[2]
//  P3 attention (hx=2, zinv computed inline from zp) -> opart[2]
//  P4 epilogue y = gamma*(op0+op1) + x
// ---------------------------------------------------------------------------
__global__ __launch_bounds__(256, 2) void k_fused(
    const float* __restrict__ x,
    const float* __restrict__ Wf, const float* __restrict__ bfv,
    const float* __restrict__ Wg, const float* __restrict__ bgv,
    const float* __restrict__ Wh, const float* __restrict__ bhv,
    const float* __restrict__ gamma,
    __hip_bfloat16* __restrict__ fb, __hip_bfloat16* __restrict__ gb,
    __hip_bfloat16* __restrict__ hb, float* __restrict__ zp,
    __hip_bfloat16* __restrict__ opart, float* __restrict__ y)
{
    __shared__ __align__(16) unsigned char smem[19712];
    cg::grid_group gg = cg::this_grid();

    const int bid = (int)blockIdx.x;
    const int tid = (int)threadIdx.x;
    const int w = tid >> 6, lane = tid & 63, quad = lane >> 4, l15 = lane & 15;
    const f32x4 cz = {0.f, 0.f, 0.f, 0.f};

    // ================= P1: 1x1 convs =================
    {
        __hip_bfloat16* xS = (__hip_bfloat16*)smem;   // [32][72] bf16
        const int b  = bid >> 7;
        const int n0 = (bid & 127) * 32;

        {   // stage x tile (32 px x 64 c) as bf16 [px][c]
            const int px = tid & 31, c0 = (tid >> 5) * 8;
            const float* xb = x + (size_t)b * (CC * HW) + n0 + px;
            float xv[8];
#pragma unroll
            for (int k = 0; k < 8; ++k) xv[k] = xb[(size_t)(c0 + k) * HW];
#pragma unroll
            for (int k = 0; k < 8; k += 2) {
                __hip_bfloat16 t2[2] = {f2bf(xv[k]), f2bf(xv[k + 1])};
                *(unsigned*)&xS[px * 72 + c0 + k] = *(const unsigned*)t2;
            }
        }
        __syncthreads();

        const int pxg = w & 1, grp = w >> 1;
        const int p = n0 + pxg * 16 + l15;   // output pixel column for this lane
        const bf16x8 xb0 = *(const bf16x8*)&xS[(pxg * 16 + l15) * 72 + quad * 8];
        const bf16x8 xb1 = *(const bf16x8*)&xS[(pxg * 16 + l15) * 72 + 32 + quad * 8];

        auto do_strip = [&](int s) {
            const int row = s * 16 + l15;
            const float* src = (row < 8) ? (Wf + row * 64)
                             : (row < 16) ? (Wg + (row - 8) * 64)
                                          : (Wh + (row - 16) * 64);
            bf16x8 wa[2];
#pragma unroll
            for (int kk = 0; kk < 2; ++kk) {
                const float4 a4 = *(const float4*)(src + kk * 32 + quad * 8);
                const float4 b4 = *(const float4*)(src + kk * 32 + quad * 8 + 4);
                __hip_bfloat16 t8[8];
                t8[0] = f2bf(a4.x); t8[1] = f2bf(a4.y); t8[2] = f2bf(a4.z); t8[3] = f2bf(a4.w);
                t8[4] = f2bf(b4.x); t8[5] = f2bf(b4.y); t8[6] = f2bf(b4.z); t8[7] = f2bf(b4.w);
                wa[kk] = *(const bf16x8*)t8;
            }
            f32x4 acc;
#pragma unroll
            for (int rr = 0; rr < 4; ++rr) {
                const int grow = s * 16 + quad * 4 + rr;
                acc[rr] = (grow < 8) ? bfv[grow]
                        : (grow < 16) ? bgv[grow - 8] : bhv[grow - 16];
            }
            acc = __builtin_amdgcn_mfma_f32_16x16x32_bf16(wa[0], xb0, acc, 0, 0, 0);
            acc = __builtin_amdgcn_mfma_f32_16x16x32_bf16(wa[1], xb1, acc, 0, 0, 0);
            if (s == 0) {
                const size_t bn = (size_t)b * HW + p;
                __hip_bfloat16* base = (quad < 2 ? fb : gb) + bn * 8 + (quad & 1) * 4;
                __hip_bfloat16 t2[2];
                t2[0] = f2bf(acc[0]); t2[1] = f2bf(acc[1]);
                *(unsigned*)&base[0] = *(const unsigned*)t2;
                t2[0] = f2bf(acc[2]); t2[1] = f2bf(acc[3]);
                *(unsigned*)&base[2] = *(const unsigned*)t2;
            } else {
#pragma unroll
                for (int rr = 0; rr < 4; ++rr) {
                    const int hrow = (s - 1) * 16 + quad * 4 + rr;
                    hb[((size_t)(b * 64 + hrow)) * HW + p] = f2bf(acc[rr]);
                }
            }
        };
        do_strip(grp ? 2 : 0);
        do_strip(grp ? 3 : 1);
        if (!grp) do_strip(4);
    }
    gg.sync();

    // ================= P2: Z partials =================
    {
        __hip_bfloat16* gS = (__hip_bfloat16*)smem;            // [64][8]
        float (*zred)[64] = (float(*)[64])(smem + 1024);       // [4][64]
        const int nt = bid >> 3, b = (bid >> 1) & 3, ich = bid & 1;
        const int n0 = nt * 64;
        if (tid < 64)
            *(float4*)&gS[tid * 8] = *(const float4*)(gb + ((size_t)b * HW + n0 + tid) * 8);
        __syncthreads();

        bf16x8 bgf[4];
#pragma unroll
        for (int ns = 0; ns < 4; ++ns) {
            bf16x8 v = {0, 0, 0, 0, 0, 0, 0, 0};
            if (quad == 0) v = *(const bf16x8*)&gS[(ns * 16 + l15) * 8];
            bgf[ns] = v;
        }
        float z[4] = {0.f, 0.f, 0.f, 0.f};
        const __hip_bfloat16* fbase = fb + ((size_t)b * HW + ich * 2048 + w * 16) * 8;
        for (int it = 0; it < 32; ++it) {
            bf16x8 afr = {0, 0, 0, 0, 0, 0, 0, 0};
            if (quad == 0) afr = *(const bf16x8*)(fbase + ((size_t)it * 64 + l15) * 8);
#pragma unroll
            for (int ns = 0; ns < 4; ++ns) {
                f32x4 s = __builtin_amdgcn_mfma_f32_16x16x32_bf16(afr, bgf[ns], cz, 0, 0, 0);
                z[ns] += __expf(s[0]) + __expf(s[1]) + __expf(s[2]) + __expf(s[3]);
            }
        }
#pragma unroll
        for (int ns = 0; ns < 4; ++ns) {
            float v = z[ns];
            v += __shfl_xor(v, 16);
            v += __shfl_xor(v, 32);
            if (quad == 0) zred[w][ns * 16 + l15] = v;
        }
        __syncthreads();
        if (tid < 64) {
            float s = zred[0][tid] + zred[1][tid] + zred[2][tid] + zred[3][tid];
            zp[((size_t)ich * NB + b) * HW + n0 + tid] = s;
        }
    }
    gg.sync();

    // ================= P3: attention =================
    {
        __hip_bfloat16* gS = (__hip_bfloat16*)smem;            // 1024 B
        float* zS = (float*)(smem + 1024);                     // 256 B
        __hip_bfloat16* hT = (__hip_bfloat16*)(smem + 1280);   // [64][72]
        __hip_bfloat16* pT = (__hip_bfloat16*)(smem + 10496);  // [64][72]

        const int hx = bid & 1, b = (bid >> 1) & 3, r = bid >> 3;
        const int mt = (r < 32) ? r : 95 - r;
        const int m0 = mt * 64;
        const int c0s = tid >> 3, ch0 = tid & 7;
        const int c1s = (256 + tid) >> 3, ch1 = (256 + tid) & 7;

        bf16x8 af = {0, 0, 0, 0, 0, 0, 0, 0};
        if (quad == 0)
            af = *(const bf16x8*)(fb + ((size_t)b * HW + m0 + w * 16 + l15) * 8);

        f32x4 accO[4];
#pragma unroll
        for (int i = 0; i < 4; ++i) accO[i] = cz;

        const int nc0 = mt + hx;
        float4 hv0 = make_float4(0.f, 0.f, 0.f, 0.f);
        float4 hv1 = hv0, gv = hv0, za = hv0, zb4 = hv0;
        if (nc0 < 64) {
            const int n1 = nc0 * 64;
            hv0 = *(const float4*)(hb + ((size_t)(b * 64 + c0s)) * HW + n1 + ch0 * 8);
            hv1 = *(const float4*)(hb + ((size_t)(b * 64 + c1s)) * HW + n1 + ch1 * 8);
            if (tid < 64) gv = *(const float4*)(gb + ((size_t)b * HW + n1 + tid) * 8);
            else if (tid < 80) {
                const int j4 = (tid - 64) * 4;
                za  = *(const float4*)(zp + ((size_t)0 * NB + b) * HW + n1 + j4);
                zb4 = *(const float4*)(zp + ((size_t)1 * NB + b) * HW + n1 + j4);
            }
        }

        for (int nc = nc0; nc < 64; nc += 2) {
            __syncthreads();
            *(float4*)&hT[c0s * 72 + ch0 * 8] = hv0;
            *(float4*)&hT[c1s * 72 + ch1 * 8] = hv1;
            if (tid < 64) *(float4*)&gS[tid * 8] = gv;
            else if (tid < 80) {
                float4 zi;
                zi.x = 1.f / (za.x + zb4.x);
                zi.y = 1.f / (za.y + zb4.y);
                zi.z = 1.f / (za.z + zb4.z);
                zi.w = 1.f / (za.w + zb4.w);
                *(float4*)&zS[(tid - 64) * 4] = zi;
            }
            const int nn = nc + 2;
            if (nn < 64) {
                const int n1 = nn * 64;
                hv0 = *(const float4*)(hb + ((size_t)(b * 64 + c0s)) * HW + n1 + ch0 * 8);
                hv1 = *(const float4*)(hb + ((size_t)(b * 64 + c1s)) * HW + n1 + ch1 * 8);
                if (tid < 64) gv = *(const float4*)(gb + ((size_t)b * HW + n1 + tid) * 8);
                else if (tid < 80) {
                    const int j4 = (tid - 64) * 4;
                    za  = *(const float4*)(zp + ((size_t)0 * NB + b) * HW + n1 + j4);
                    zb4 = *(const float4*)(zp + ((size_t)1 * NB + b) * HW + n1 + j4);
                }
            }
            __syncthreads();

            const int n0c = nc * 64;
            const bool diag = (nc == mt);
            // phase A: s = f.g^T; p = exp(s)*zinv; mask; -> pT (wave-private rows)
#pragma unroll
            for (int ns = 0; ns < 4; ++ns) {
                bf16x8 bg2 = {0, 0, 0, 0, 0, 0, 0, 0};
                if (quad == 0) bg2 = *(const bf16x8*)&gS[(ns * 16 + l15) * 8];
                f32x4 s = __builtin_amdgcn_mfma_f32_16x16x32_bf16(af, bg2, cz, 0, 0, 0);
                const float zi = zS[ns * 16 + l15];
#pragma unroll
                for (int j = 0; j < 4; ++j) {
                    float p = __expf(s[j]) * zi;
                    if (diag) {
                        const int m = m0 + w * 16 + quad * 4 + j;
                        const int n = n0c + ns * 16 + l15;
                        if (n < m) p = 0.f;
                    }
                    pT[(w * 16 + quad * 4 + j) * 72 + ns * 16 + l15] = f2bf(p);
                }
            }
            // phase B: accO += P x H
#pragma unroll
            for (int kb = 0; kb < 2; ++kb) {
                const bf16x8 ap =
                    *(const bf16x8*)&pT[(w * 16 + l15) * 72 + kb * 32 + quad * 8];
#pragma unroll
                for (int cs = 0; cs < 4; ++cs) {
                    const bf16x8 bh2 =
                        *(const bf16x8*)&hT[(cs * 16 + l15) * 72 + kb * 32 + quad * 8];
                    accO[cs] = __builtin_amdgcn_mfma_f32_16x16x32_bf16(ap, bh2, accO[cs], 0, 0, 0);
                }
            }
        }

        // epilogue: bf16 partial tile, opart[hx][b][c][m]
#pragma unroll
        for (int cs = 0; cs < 4; ++cs) {
            const int c = cs * 16 + l15;
            __hip_bfloat16 tmp[4];
#pragma unroll
            for (int j = 0; j < 4; ++j) tmp[j] = f2bf(accO[cs][j]);
            *(float2*)(opart + ((size_t)((hx * NB + b) * 64 + c)) * HW + m0 + w * 16 + quad * 4) =
                *(const float2*)tmp;
        }
    }
    gg.sync();

    // ================= P4: epilogue =================
    {
        const int t = bid * 256 + tid;           // 131072 threads, 8 el each
        const size_t e0 = (size_t)t * 8;
        const float ga = gamma[0];
        float acc[8] = {0, 0, 0, 0, 0, 0, 0, 0};
#pragma unroll
        for (int h = 0; h < 2; ++h) {
            const bf16x8 v = *(const bf16x8*)(opart + (size_t)h * (NB * CC * HW) + e0);
#pragma unroll
            for (int k = 0; k < 8; ++k) acc[k] += bf2f(v[k]);
        }
        const float4 x0 = *(const float4*)(x + e0);
        const float4 x1 = *(const float4*)(x + e0 + 4);
        float4 y0, y1;
        y0.x = ga * acc[0] + x0.x; y0.y = ga * acc[1] + x0.y;
        y0.z = ga * acc[2] + x0.z; y0.w = ga * acc[3] + x0.w;
        y1.x = ga * acc[4] + x1.x; y1.y = ga * acc[5] + x1.y;
        y1.z = ga * acc[6] + x1.z; y1.w = ga * acc[7] + x1.w;
        *(float4*)(y + e0) = y0;
        *(float4*)(y + e0 + 4) = y1;
    }
}

extern "C" void kernel_launch(void* const* d_in, const int* in_sizes, int n_in,
                              void* d_out, int out_size, void* d_ws, size_t ws_size,
                              hipStream_t stream)
{
    const float* x     = (const float*)d_in[0];
    const float* Wf    = (const float*)d_in[1];
    const float* bfv   = (const float*)d_in[2];
    const float* Wg    = (const float*)d_in[3];
    const float* bgv   = (const float*)d_in[4];
    const float* Wh    = (const float*)d_in[5];
    const float* bhv   = (const float*)d_in[6];
    const float* gamma = (const float*)d_in[7];

    char* ws = (char*)d_ws;
    __hip_bfloat16* fb = (__hip_bfloat16*)(ws + OFF_F);
    __hip_bfloat16* gb = (__hip_bfloat16*)(ws + OFF_G);
    __hip_bfloat16* hb = (__hip_bfloat16*)(ws + OFF_H);
    float* zp          = (float*)(ws + OFF_ZP);
    __hip_bfloat16* opart = (__hip_bfloat16*)(ws + OFF_O);
    float* y = (float*)d_out;

    void* kargs[] = { (void*)&x, (void*)&Wf, (void*)&bfv, (void*)&Wg, (void*)&bgv,
                      (void*)&Wh, (void*)&bhv, (void*)&gamma,
                      (void*)&fb, (void*)&gb, (void*)&hb, (void*)&zp,
                      (void*)&opart, (void*)&y };
    hipLaunchCooperativeKernel((void*)k_fused, dim3(512), dim3(256), kargs, 0, stream);
}

// Round 8
// 127.480 us; speedup vs baseline: 2.2255x; 2.2255x over previous
//
#include <hip/hip_runtime.h>
#include <hip/hip_bf16.h>

#define HW 4096
#define CC 64
#define NB 4

typedef short bf16x8 __attribute__((ext_vector_type(8)));
typedef short bf16x4 __attribute__((ext_vector_type(4)));
typedef float f32x4 __attribute__((ext_vector_type(4)));

// workspace layout (byte offsets)
#define OFF_F  0                      // bf16 [b][n][8]      262144 B
#define OFF_G  262144                 // bf16 [b][n][8]      262144 B
#define OFF_H  524288                 // bf16 [b][c][n]     2097152 B
#define OFF_ZP 2621440                // f32  [2ich][b][n]   131072 B
#define OFF_O  2752512                // bf16 [2hx][b][c][m] 4194304 B
// end ~6.9 MB

__device__ __forceinline__ float bf2f(short s) {
    unsigned u = ((unsigned)(unsigned short)s) << 16;
    return __uint_as_float(u);
}
__device__ __forceinline__ __hip_bfloat16 f2bf(float f) { return __float2bfloat16(f); }

// ---------------------------------------------------------------------------
// Kernel 1 (MFMA): Y[80,64] = W_all @ X[64,64px] + bias per 64-pixel tile.
// Same as R6 (measured good): W A-frags in registers, x staged transposed.
// ---------------------------------------------------------------------------
__global__ __launch_bounds__(256) void k_prep(
    const float* __restrict__ x,
    const float* __restrict__ Wf, const float* __restrict__ bfv,
    const float* __restrict__ Wg, const float* __restrict__ bgv,
    const float* __restrict__ Wh, const float* __restrict__ bhv,
    __hip_bfloat16* __restrict__ fb, __hip_bfloat16* __restrict__ gb,
    __hip_bfloat16* __restrict__ hb)
{
    __shared__ __align__(16) __hip_bfloat16 xT[64 * 72];
    __shared__ __align__(16) __hip_bfloat16 fgT[64 * 24];

    const int b  = blockIdx.y;
    const int n0 = blockIdx.x * 64;
    const int tid = (int)threadIdx.x;
    const int w = tid >> 6, lane = tid & 63, quad = lane >> 4, l15 = lane & 15;

    {
        const int n = lane;
        const float* xb = x + (size_t)b * (CC * HW) + n0 + n;
#pragma unroll
        for (int i = 0; i < 8; ++i) {
            const int c = (w + 4 * i) * 2;
            const float v0 = xb[(size_t)c * HW];
            const float v1 = xb[(size_t)(c + 1) * HW];
            __hip_bfloat16 t[2] = {f2bf(v0), f2bf(v1)};
            *(unsigned*)&xT[n * 72 + c] = *(const unsigned*)t;
        }
    }

    bf16x8 wa[5][2];
#pragma unroll
    for (int mt = 0; mt < 5; ++mt) {
        const int row = mt * 16 + l15;
        const float* src = (row < 8) ? (Wf + row * 64)
                         : (row < 16) ? (Wg + (row - 8) * 64)
                                      : (Wh + (row - 16) * 64);
#pragma unroll
        for (int kk = 0; kk < 2; ++kk) {
            const float4 a = *(const float4*)(src + kk * 32 + quad * 8);
            const float4 c4 = *(const float4*)(src + kk * 32 + quad * 8 + 4);
            __hip_bfloat16 t[8];
            t[0] = f2bf(a.x);  t[1] = f2bf(a.y);  t[2] = f2bf(a.z);  t[3] = f2bf(a.w);
            t[4] = f2bf(c4.x); t[5] = f2bf(c4.y); t[6] = f2bf(c4.z); t[7] = f2bf(c4.w);
            wa[mt][kk] = *(const bf16x8*)t;
        }
    }

    f32x4 acc[5];
#pragma unroll
    for (int mt = 0; mt < 5; ++mt) {
#pragma unroll
        for (int r = 0; r < 4; ++r) {
            const int grow = mt * 16 + quad * 4 + r;
            acc[mt][r] = (grow < 8) ? bfv[grow]
                       : (grow < 16) ? bgv[grow - 8] : bhv[grow - 16];
        }
    }

    __syncthreads();

    const bf16x8 b0 = *(const bf16x8*)&xT[(w * 16 + l15) * 72 + quad * 8];
    const bf16x8 b1 = *(const bf16x8*)&xT[(w * 16 + l15) * 72 + 32 + quad * 8];
#pragma unroll
    for (int mt = 0; mt < 5; ++mt) {
        acc[mt] = __builtin_amdgcn_mfma_f32_16x16x32_bf16(wa[mt][0], b0, acc[mt], 0, 0, 0);
        acc[mt] = __builtin_amdgcn_mfma_f32_16x16x32_bf16(wa[mt][1], b1, acc[mt], 0, 0, 0);
    }

#pragma unroll
    for (int mt = 1; mt < 5; ++mt) {
#pragma unroll
        for (int r = 0; r < 4; ++r) {
            const int hrow = (mt - 1) * 16 + quad * 4 + r;
            hb[((size_t)(b * 64 + hrow)) * HW + n0 + w * 16 + l15] = f2bf(acc[mt][r]);
        }
    }

#pragma unroll
    for (int r = 0; r < 4; r += 2) {
        __hip_bfloat16 t[2] = {f2bf(acc[0][r]), f2bf(acc[0][r + 1])};
        *(unsigned*)&fgT[(w * 16 + l15) * 24 + quad * 4 + r] = *(const unsigned*)t;
    }
    __syncthreads();
    if (tid < 64) {
        const size_t bn = (size_t)b * HW + n0 + tid;
        *(float4*)(fb + bn * 8) = *(const float4*)&fgT[tid * 24];
    } else if (tid < 128) {
        const int n = tid - 64;
        const size_t bn = (size_t)b * HW + n0 + n;
        *(float4*)(gb + bn * 8) = *(const float4*)&fgT[n * 24 + 8];
    }
}

// ---------------------------------------------------------------------------
// Kernel 2: Z partials. Grid (64nt, 4b, 2ich) = 512 blocks (2/CU).
// Stages this block's 2048-row f half (32 KB) in LDS; register prefetch
// breaks the per-iter LDS->MFMA->exp serial chain.
// ---------------------------------------------------------------------------
__global__ __launch_bounds__(256) void k_z(
    const __hip_bfloat16* __restrict__ fb, const __hip_bfloat16* __restrict__ gb,
    float* __restrict__ zp)
{
    __shared__ __align__(16) __hip_bfloat16 fS[2048 * 8];   // 32 KB
    __shared__ __align__(16) __hip_bfloat16 gS[64 * 8];
    __shared__ float zred[4][64];

    const int nt = blockIdx.x, b = blockIdx.y, ich = blockIdx.z;
    const int n0 = nt * 64;
    const int tid = (int)threadIdx.x;
    const int w = tid >> 6, lane = tid & 63, quad = lane >> 4, l15 = lane & 15;

    const float4* fsrc = (const float4*)(fb + ((size_t)b * HW + ich * 2048) * 8);
#pragma unroll
    for (int q = 0; q < 8; ++q)
        ((float4*)fS)[q * 256 + tid] = fsrc[q * 256 + tid];
    if (tid < 64)
        *(float4*)&gS[tid * 8] = *(const float4*)(gb + ((size_t)b * HW + n0 + tid) * 8);
    __syncthreads();

    const f32x4 cz = {0.f, 0.f, 0.f, 0.f};
    bf16x8 bgf[4];
#pragma unroll
    for (int ns = 0; ns < 4; ++ns) {
        bf16x8 v = {0, 0, 0, 0, 0, 0, 0, 0};
        if (quad == 0) v = *(const bf16x8*)&gS[(ns * 16 + l15) * 8];
        bgf[ns] = v;
    }

    float z[4] = {0.f, 0.f, 0.f, 0.f};
    bf16x8 cur = {0, 0, 0, 0, 0, 0, 0, 0};
    if (quad == 0) cur = *(const bf16x8*)&fS[(w * 16 + l15) * 8];
    for (int it = 0; it < 32; ++it) {
        bf16x8 nxt = {0, 0, 0, 0, 0, 0, 0, 0};
        if (it + 1 < 32 && quad == 0)
            nxt = *(const bf16x8*)&fS[((it + 1) * 64 + w * 16 + l15) * 8];
#pragma unroll
        for (int ns = 0; ns < 4; ++ns) {
            f32x4 s = __builtin_amdgcn_mfma_f32_16x16x32_bf16(cur, bgf[ns], cz, 0, 0, 0);
            z[ns] += __expf(s[0]) + __expf(s[1]) + __expf(s[2]) + __expf(s[3]);
        }
        cur = nxt;
    }

#pragma unroll
    for (int ns = 0; ns < 4; ++ns) {
        float v = z[ns];
        v += __shfl_xor(v, 16);
        v += __shfl_xor(v, 32);
        if (quad == 0) zred[w][ns * 16 + l15] = v;
    }
    __syncthreads();
    if (tid < 64) {
        float s = zred[0][tid] + zred[1][tid] + zred[2][tid] + zred[3][tid];
        zp[((size_t)ich * NB + b) * HW + n0 + tid] = s;
    }
}

// ---------------------------------------------------------------------------
// Kernel 3: attention, hx=2. Phase A computes s^T = g.f^T so each lane's 4
// P-values are column-contiguous -> ONE ds_write_b64 per ns (was 16 scalar
// b16 writes/chunk). zinv folded from 2 zp partials at staging. Partial-o
// bf16 tiles per (hx,b,mt) block; reduced in k_epi.
// ---------------------------------------------------------------------------
__global__ __launch_bounds__(256) void k_attn(
    const __hip_bfloat16* __restrict__ fb, const __hip_bfloat16* __restrict__ gb,
    const __hip_bfloat16* __restrict__ hb, const float* __restrict__ zp,
    __hip_bfloat16* __restrict__ opart)
{
    __shared__ __align__(16) __hip_bfloat16 gS[64 * 8];
    __shared__ __align__(16) float zS[64];
    __shared__ __align__(16) __hip_bfloat16 hT[64 * 72];
    __shared__ __align__(16) __hip_bfloat16 pT[64 * 72];

    const int hx = blockIdx.x;               // 0..1 n-parity split
    const int b  = blockIdx.y;
    const int r  = blockIdx.z;
    const int mt = (r < 32) ? r : 95 - r;    // fold for load balance
    const int m0 = mt * 64;
    const int tid = (int)threadIdx.x;
    const int w = tid >> 6, lane = tid & 63, quad = lane >> 4, l15 = lane & 15;

    const int c0s = tid >> 3,         ch0 = tid & 7;
    const int c1s = (256 + tid) >> 3, ch1 = (256 + tid) & 7;

    const f32x4 cz = {0.f, 0.f, 0.f, 0.f};

    bf16x8 af = {0, 0, 0, 0, 0, 0, 0, 0};
    if (quad == 0)
        af = *(const bf16x8*)(fb + ((size_t)b * HW + m0 + w * 16 + l15) * 8);

    f32x4 accO[4];
#pragma unroll
    for (int i = 0; i < 4; ++i) accO[i] = cz;

    const int nc0 = mt + hx;
    float4 hv0 = make_float4(0.f, 0.f, 0.f, 0.f);
    float4 hv1 = hv0, gv = hv0, za = hv0, zb4 = hv0;
    if (nc0 < 64) {
        const int n1 = nc0 * 64;
        hv0 = *(const float4*)(hb + ((size_t)(b * 64 + c0s)) * HW + n1 + ch0 * 8);
        hv1 = *(const float4*)(hb + ((size_t)(b * 64 + c1s)) * HW + n1 + ch1 * 8);
        if (tid < 64) gv = *(const float4*)(gb + ((size_t)b * HW + n1 + tid) * 8);
        else if (tid < 80) {
            const int j4 = (tid - 64) * 4;
            za  = *(const float4*)(zp + (size_t)b * HW + n1 + j4);
            zb4 = *(const float4*)(zp + ((size_t)NB + b) * HW + n1 + j4);
        }
    }

    for (int nc = nc0; nc < 64; nc += 2) {
        __syncthreads();
        *(float4*)&hT[c0s * 72 + ch0 * 8] = hv0;
        *(float4*)&hT[c1s * 72 + ch1 * 8] = hv1;
        if (tid < 64) *(float4*)&gS[tid * 8] = gv;
        else if (tid < 80) {
            float4 zi;
            zi.x = 1.f / (za.x + zb4.x);
            zi.y = 1.f / (za.y + zb4.y);
            zi.z = 1.f / (za.z + zb4.z);
            zi.w = 1.f / (za.w + zb4.w);
            *(float4*)&zS[(tid - 64) * 4] = zi;
        }
        const int nn = nc + 2;
        if (nn < 64) {
            const int n1 = nn * 64;
            hv0 = *(const float4*)(hb + ((size_t)(b * 64 + c0s)) * HW + n1 + ch0 * 8);
            hv1 = *(const float4*)(hb + ((size_t)(b * 64 + c1s)) * HW + n1 + ch1 * 8);
            if (tid < 64) gv = *(const float4*)(gb + ((size_t)b * HW + n1 + tid) * 8);
            else if (tid < 80) {
                const int j4 = (tid - 64) * 4;
                za  = *(const float4*)(zp + (size_t)b * HW + n1 + j4);
                zb4 = *(const float4*)(zp + ((size_t)NB + b) * HW + n1 + j4);
            }
        }
        __syncthreads();

        const int n0c = nc * 64;
        const bool diag = (nc == mt);
        // ---- phase A (transposed): sT = g.f^T; lane holds n=quad*4+j, m=l15
#pragma unroll
        for (int ns = 0; ns < 4; ++ns) {
            bf16x8 bg2 = {0, 0, 0, 0, 0, 0, 0, 0};
            if (quad == 0) bg2 = *(const bf16x8*)&gS[(ns * 16 + l15) * 8];
            f32x4 s = __builtin_amdgcn_mfma_f32_16x16x32_bf16(bg2, af, cz, 0, 0, 0);
            const float4 zi4 = *(const float4*)&zS[ns * 16 + quad * 4];
            __hip_bfloat16 t4[4];
#pragma unroll
            for (int j = 0; j < 4; ++j) {
                float p = __expf(s[j]) * ((const float*)&zi4)[j];
                if (diag) {
                    const int n = n0c + ns * 16 + quad * 4 + j;
                    const int m = m0 + w * 16 + l15;
                    if (n < m) p = 0.f;
                }
                t4[j] = f2bf(p);
            }
            *(bf16x4*)&pT[(w * 16 + l15) * 72 + ns * 16 + quad * 4] = *(const bf16x4*)t4;
        }
        // ---- phase B: accO += P x H (pT rows wave-private, no barrier) ----
#pragma unroll
        for (int kb = 0; kb < 2; ++kb) {
            const bf16x8 ap =
                *(const bf16x8*)&pT[(w * 16 + l15) * 72 + kb * 32 + quad * 8];
#pragma unroll
            for (int cs = 0; cs < 4; ++cs) {
                const bf16x8 bh2 =
                    *(const bf16x8*)&hT[(cs * 16 + l15) * 72 + kb * 32 + quad * 8];
                accO[cs] = __builtin_amdgcn_mfma_f32_16x16x32_bf16(ap, bh2, accO[cs], 0, 0, 0);
            }
        }
    }

    // ---- epilogue: bf16 partial tile, opart[hx][b][c][m] ----
#pragma unroll
    for (int cs = 0; cs < 4; ++cs) {
        const int c = cs * 16 + l15;
        __hip_bfloat16 tmp[4];
#pragma unroll
        for (int j = 0; j < 4; ++j) tmp[j] = f2bf(accO[cs][j]);
        *(float2*)(opart + ((size_t)((hx * NB + b) * 64 + c)) * HW + m0 + w * 16 + quad * 4) =
            *(const float2*)tmp;
    }
}

// ---------------------------------------------------------------------------
// Kernel 4: y = gamma * (op0 + op1) + x.  131072 threads x 8 el = 512 blocks.
// ---------------------------------------------------------------------------
__global__ __launch_bounds__(256) void k_epi(
    const __hip_bfloat16* __restrict__ opart, const float* __restrict__ x,
    const float* __restrict__ gamma, float* __restrict__ y)
{
    const int t = blockIdx.x * 256 + (int)threadIdx.x;
    const size_t e0 = (size_t)t * 8;
    const float ga = gamma[0];

    float acc[8] = {0, 0, 0, 0, 0, 0, 0, 0};
#pragma unroll
    for (int h = 0; h < 2; ++h) {
        const bf16x8 v = *(const bf16x8*)(opart + (size_t)h * (NB * CC * HW) + e0);
#pragma unroll
        for (int k = 0; k < 8; ++k) acc[k] += bf2f(v[k]);
    }
    const float4 x0 = *(const float4*)(x + e0);
    const float4 x1 = *(const float4*)(x + e0 + 4);
    float4 y0, y1;
    y0.x = ga * acc[0] + x0.x; y0.y = ga * acc[1] + x0.y;
    y0.z = ga * acc[2] + x0.z; y0.w = ga * acc[3] + x0.w;
    y1.x = ga * acc[4] + x1.x; y1.y = ga * acc[5] + x1.y;
    y1.z = ga * acc[6] + x1.z; y1.w = ga * acc[7] + x1.w;
    *(float4*)(y + e0) = y0;
    *(float4*)(y + e0 + 4) = y1;
}

extern "C" void kernel_launch(void* const* d_in, const int* in_sizes, int n_in,
                              void* d_out, int out_size, void* d_ws, size_t ws_size,
                              hipStream_t stream)
{
    const float* x     = (const float*)d_in[0];
    const float* Wf    = (const float*)d_in[1];
    const float* bfv   = (const float*)d_in[2];
    const float* Wg    = (const float*)d_in[3];
    const float* bgv   = (const float*)d_in[4];
    const float* Wh    = (const float*)d_in[5];
    const float* bhv   = (const float*)d_in[6];
    const float* gamma = (const float*)d_in[7];

    char* ws = (char*)d_ws;
    __hip_bfloat16* fb = (__hip_bfloat16*)(ws + OFF_F);
    __hip_bfloat16* gb = (__hip_bfloat16*)(ws + OFF_G);
    __hip_bfloat16* hb = (__hip_bfloat16*)(ws + OFF_H);
    float* zp          = (float*)(ws + OFF_ZP);
    __hip_bfloat16* opart = (__hip_bfloat16*)(ws + OFF_O);
    float* y = (float*)d_out;

    k_prep<<<dim3(64, 4), 256, 0, stream>>>(x, Wf, bfv, Wg, bgv, Wh, bhv, fb, gb, hb);
    k_z<<<dim3(64, 4, 2), 256, 0, stream>>>(fb, gb, zp);
    k_attn<<<dim3(2, 4, 64), 256, 0, stream>>>(fb, gb, hb, zp, opart);
    k_epi<<<512, 256, 0, stream>>>(opart, x, gamma, y);
}

// Round 9
// 120.963 us; speedup vs baseline: 2.3454x; 1.0539x over previous
//
#include <hip/hip_runtime.h>
#include <hip/hip_bf16.h>

#define HW 4096
#define CC 64
#define NB 4

typedef short bf16x8 __attribute__((ext_vector_type(8)));
typedef short bf16x4 __attribute__((ext_vector_type(4)));
typedef float f32x4 __attribute__((ext_vector_type(4)));

// workspace layout (byte offsets)
#define OFF_F  0                      // bf16 [b][n][8]      262144 B
#define OFF_G  262144                 // bf16 [b][n][8]      262144 B
#define OFF_H  524288                 // bf16 [b][c][n]     2097152 B
#define OFF_ZP 2621440                // f32  [2ich][b][n]   131072 B
#define OFF_O  2752512                // bf16 [8hx][b][c][m] 16777216 B
// end ~19.5 MB

__device__ __forceinline__ float bf2f(short s) {
    unsigned u = ((unsigned)(unsigned short)s) << 16;
    return __uint_as_float(u);
}
__device__ __forceinline__ __hip_bfloat16 f2bf(float f) { return __float2bfloat16(f); }

// ---------------------------------------------------------------------------
// Kernel 1 (MFMA): 32-px tiles, 512 blocks (2/CU). W A-frags in registers,
// x staged transposed bf16. Waves 0-1: strips 0(f/g),1,4; waves 2-3: 2,3.
// ---------------------------------------------------------------------------
__global__ __launch_bounds__(256) void k_prep(
    const float* __restrict__ x,
    const float* __restrict__ Wf, const float* __restrict__ bfv,
    const float* __restrict__ Wg, const float* __restrict__ bgv,
    const float* __restrict__ Wh, const float* __restrict__ bhv,
    __hip_bfloat16* __restrict__ fb, __hip_bfloat16* __restrict__ gb,
    __hip_bfloat16* __restrict__ hb)
{
    __shared__ __align__(16) __hip_bfloat16 xS[32 * 72];

    const int b  = blockIdx.y;
    const int n0 = blockIdx.x * 32;
    const int tid = (int)threadIdx.x;
    const int w = tid >> 6, lane = tid & 63, quad = lane >> 4, l15 = lane & 15;

    {   // stage x tile (32 px x 64 c) as bf16 [px][c]
        const int px = tid & 31, c0 = (tid >> 5) * 8;
        const float* xb = x + (size_t)b * (CC * HW) + n0 + px;
        float xv[8];
#pragma unroll
        for (int k = 0; k < 8; ++k) xv[k] = xb[(size_t)(c0 + k) * HW];
#pragma unroll
        for (int k = 0; k < 8; k += 2) {
            __hip_bfloat16 t2[2] = {f2bf(xv[k]), f2bf(xv[k + 1])};
            *(unsigned*)&xS[px * 72 + c0 + k] = *(const unsigned*)t2;
        }
    }
    __syncthreads();

    const int pxg = w & 1, grp = w >> 1;
    const int p = n0 + pxg * 16 + l15;
    const bf16x8 xb0 = *(const bf16x8*)&xS[(pxg * 16 + l15) * 72 + quad * 8];
    const bf16x8 xb1 = *(const bf16x8*)&xS[(pxg * 16 + l15) * 72 + 32 + quad * 8];

    auto do_strip = [&](int s) {
        const int row = s * 16 + l15;
        const float* src = (row < 8) ? (Wf + row * 64)
                         : (row < 16) ? (Wg + (row - 8) * 64)
                                      : (Wh + (row - 16) * 64);
        bf16x8 wa[2];
#pragma unroll
        for (int kk = 0; kk < 2; ++kk) {
            const float4 a4 = *(const float4*)(src + kk * 32 + quad * 8);
            const float4 b4 = *(const float4*)(src + kk * 32 + quad * 8 + 4);
            __hip_bfloat16 t8[8];
            t8[0] = f2bf(a4.x); t8[1] = f2bf(a4.y); t8[2] = f2bf(a4.z); t8[3] = f2bf(a4.w);
            t8[4] = f2bf(b4.x); t8[5] = f2bf(b4.y); t8[6] = f2bf(b4.z); t8[7] = f2bf(b4.w);
            wa[kk] = *(const bf16x8*)t8;
        }
        f32x4 acc;
#pragma unroll
        for (int rr = 0; rr < 4; ++rr) {
            const int grow = s * 16 + quad * 4 + rr;
            acc[rr] = (grow < 8) ? bfv[grow]
                    : (grow < 16) ? bgv[grow - 8] : bhv[grow - 16];
        }
        acc = __builtin_amdgcn_mfma_f32_16x16x32_bf16(wa[0], xb0, acc, 0, 0, 0);
        acc = __builtin_amdgcn_mfma_f32_16x16x32_bf16(wa[1], xb1, acc, 0, 0, 0);
        if (s == 0) {
            const size_t bn = (size_t)b * HW + p;
            __hip_bfloat16* base = (quad < 2 ? fb : gb) + bn * 8 + (quad & 1) * 4;
            __hip_bfloat16 t2[2];
            t2[0] = f2bf(acc[0]); t2[1] = f2bf(acc[1]);
            *(unsigned*)&base[0] = *(const unsigned*)t2;
            t2[0] = f2bf(acc[2]); t2[1] = f2bf(acc[3]);
            *(unsigned*)&base[2] = *(const unsigned*)t2;
        } else {
#pragma unroll
            for (int rr = 0; rr < 4; ++rr) {
                const int hrow = (s - 1) * 16 + quad * 4 + rr;
                hb[((size_t)(b * 64 + hrow)) * HW + p] = f2bf(acc[rr]);
            }
        }
    };
    do_strip(grp ? 2 : 0);
    do_strip(grp ? 3 : 1);
    if (!grp) do_strip(4);
}

// ---------------------------------------------------------------------------
// Kernel 2: Z partials. Grid (64nt, 4b, 2ich) = 512 blocks (2/CU).
// 32 KB f half staged in LDS; register prefetch breaks the serial chain.
// ---------------------------------------------------------------------------
__global__ __launch_bounds__(256) void k_z(
    const __hip_bfloat16* __restrict__ fb, const __hip_bfloat16* __restrict__ gb,
    float* __restrict__ zp)
{
    __shared__ __align__(16) __hip_bfloat16 fS[2048 * 8];
    __shared__ __align__(16) __hip_bfloat16 gS[64 * 8];
    __shared__ float zred[4][64];

    const int nt = blockIdx.x, b = blockIdx.y, ich = blockIdx.z;
    const int n0 = nt * 64;
    const int tid = (int)threadIdx.x;
    const int w = tid >> 6, lane = tid & 63, quad = lane >> 4, l15 = lane & 15;

    const float4* fsrc = (const float4*)(fb + ((size_t)b * HW + ich * 2048) * 8);
#pragma unroll
    for (int q = 0; q < 8; ++q)
        ((float4*)fS)[q * 256 + tid] = fsrc[q * 256 + tid];
    if (tid < 64)
        *(float4*)&gS[tid * 8] = *(const float4*)(gb + ((size_t)b * HW + n0 + tid) * 8);
    __syncthreads();

    const f32x4 cz = {0.f, 0.f, 0.f, 0.f};
    bf16x8 bgf[4];
#pragma unroll
    for (int ns = 0; ns < 4; ++ns) {
        bf16x8 v = {0, 0, 0, 0, 0, 0, 0, 0};
        if (quad == 0) v = *(const bf16x8*)&gS[(ns * 16 + l15) * 8];
        bgf[ns] = v;
    }

    float z[4] = {0.f, 0.f, 0.f, 0.f};
    bf16x8 cur = {0, 0, 0, 0, 0, 0, 0, 0};
    if (quad == 0) cur = *(const bf16x8*)&fS[(w * 16 + l15) * 8];
    for (int it = 0; it < 32; ++it) {
        bf16x8 nxt = {0, 0, 0, 0, 0, 0, 0, 0};
        if (it + 1 < 32 && quad == 0)
            nxt = *(const bf16x8*)&fS[((it + 1) * 64 + w * 16 + l15) * 8];
#pragma unroll
        for (int ns = 0; ns < 4; ++ns) {
            f32x4 s = __builtin_amdgcn_mfma_f32_16x16x32_bf16(cur, bgf[ns], cz, 0, 0, 0);
            z[ns] += __expf(s[0]) + __expf(s[1]) + __expf(s[2]) + __expf(s[3]);
        }
        cur = nxt;
    }

#pragma unroll
    for (int ns = 0; ns < 4; ++ns) {
        float v = z[ns];
        v += __shfl_xor(v, 16);
        v += __shfl_xor(v, 32);
        if (quad == 0) zred[w][ns * 16 + l15] = v;
    }
    __syncthreads();
    if (tid < 64) {
        float s = zred[0][tid] + zred[1][tid] + zred[2][tid] + zred[3][tid];
        zp[((size_t)ich * NB + b) * HW + n0 + tid] = s;
    }
}

// ---------------------------------------------------------------------------
// Kernel 3: attention, PAIRED TILES. Block (hx,b,mtp) owns mtA=mtp and
// mtB=63-mtp; loops nc in [mtA,64) with nc%8==hx. Work/block = 65/8 chunks
// for EVERY block (flat makespan). g/h/zinv staging shared by both tiles;
// pT reused sequentially (wave-private rows, no extra barrier).
// ---------------------------------------------------------------------------
__global__ __launch_bounds__(256) void k_attn(
    const __hip_bfloat16* __restrict__ fb, const __hip_bfloat16* __restrict__ gb,
    const __hip_bfloat16* __restrict__ hb, const float* __restrict__ zp,
    __hip_bfloat16* __restrict__ opart)
{
    __shared__ __align__(16) __hip_bfloat16 gS[64 * 8];
    __shared__ __align__(16) float zS[64];
    __shared__ __align__(16) __hip_bfloat16 hT[64 * 72];
    __shared__ __align__(16) __hip_bfloat16 pT[64 * 72];

    const int hx  = blockIdx.x;              // 0..7 n-residue split
    const int b   = blockIdx.y;
    const int mtA = blockIdx.z;              // 0..31
    const int mtB = 63 - mtA;
    const int m0A = mtA * 64, m0B = mtB * 64;
    const int tid = (int)threadIdx.x;
    const int w = tid >> 6, lane = tid & 63, quad = lane >> 4, l15 = lane & 15;

    const int c0s = tid >> 3,         ch0 = tid & 7;
    const int c1s = (256 + tid) >> 3, ch1 = (256 + tid) & 7;

    const f32x4 cz = {0.f, 0.f, 0.f, 0.f};

    bf16x8 afA = {0, 0, 0, 0, 0, 0, 0, 0}, afB = afA;
    if (quad == 0) {
        afA = *(const bf16x8*)(fb + ((size_t)b * HW + m0A + w * 16 + l15) * 8);
        afB = *(const bf16x8*)(fb + ((size_t)b * HW + m0B + w * 16 + l15) * 8);
    }

    f32x4 accA[4], accB[4];
#pragma unroll
    for (int i = 0; i < 4; ++i) { accA[i] = cz; accB[i] = cz; }

    const int nc0 = mtA + (((hx - (mtA & 7)) + 8) & 7);   // first nc>=mtA, %8==hx

    float4 hv0 = make_float4(0.f, 0.f, 0.f, 0.f);
    float4 hv1 = hv0, gv = hv0, za = hv0, zb4 = hv0;
    {
        const int n1 = nc0 * 64;
        hv0 = *(const float4*)(hb + ((size_t)(b * 64 + c0s)) * HW + n1 + ch0 * 8);
        hv1 = *(const float4*)(hb + ((size_t)(b * 64 + c1s)) * HW + n1 + ch1 * 8);
        if (tid < 64) gv = *(const float4*)(gb + ((size_t)b * HW + n1 + tid) * 8);
        else if (tid < 80) {
            const int j4 = (tid - 64) * 4;
            za  = *(const float4*)(zp + (size_t)b * HW + n1 + j4);
            zb4 = *(const float4*)(zp + ((size_t)NB + b) * HW + n1 + j4);
        }
    }

    for (int nc = nc0; nc < 64; nc += 8) {
        __syncthreads();
        *(float4*)&hT[c0s * 72 + ch0 * 8] = hv0;
        *(float4*)&hT[c1s * 72 + ch1 * 8] = hv1;
        if (tid < 64) *(float4*)&gS[tid * 8] = gv;
        else if (tid < 80) {
            float4 zi;
            zi.x = 1.f / (za.x + zb4.x);
            zi.y = 1.f / (za.y + zb4.y);
            zi.z = 1.f / (za.z + zb4.z);
            zi.w = 1.f / (za.w + zb4.w);
            *(float4*)&zS[(tid - 64) * 4] = zi;
        }
        const int nn = nc + 8;
        if (nn < 64) {
            const int n1 = nn * 64;
            hv0 = *(const float4*)(hb + ((size_t)(b * 64 + c0s)) * HW + n1 + ch0 * 8);
            hv1 = *(const float4*)(hb + ((size_t)(b * 64 + c1s)) * HW + n1 + ch1 * 8);
            if (tid < 64) gv = *(const float4*)(gb + ((size_t)b * HW + n1 + tid) * 8);
            else if (tid < 80) {
                const int j4 = (tid - 64) * 4;
                za  = *(const float4*)(zp + (size_t)b * HW + n1 + j4);
                zb4 = *(const float4*)(zp + ((size_t)NB + b) * HW + n1 + j4);
            }
        }
        __syncthreads();

        const int n0c = nc * 64;

        // ---- tile A: phase A (transposed) then phase B ----
        {
            const bool diag = (nc == mtA);
#pragma unroll
            for (int ns = 0; ns < 4; ++ns) {
                bf16x8 bg2 = {0, 0, 0, 0, 0, 0, 0, 0};
                if (quad == 0) bg2 = *(const bf16x8*)&gS[(ns * 16 + l15) * 8];
                f32x4 s = __builtin_amdgcn_mfma_f32_16x16x32_bf16(bg2, afA, cz, 0, 0, 0);
                const float4 zi4 = *(const float4*)&zS[ns * 16 + quad * 4];
                __hip_bfloat16 t4[4];
#pragma unroll
                for (int j = 0; j < 4; ++j) {
                    float p = __expf(s[j]) * ((const float*)&zi4)[j];
                    if (diag) {
                        const int n = n0c + ns * 16 + quad * 4 + j;
                        const int m = m0A + w * 16 + l15;
                        if (n < m) p = 0.f;
                    }
                    t4[j] = f2bf(p);
                }
                *(bf16x4*)&pT[(w * 16 + l15) * 72 + ns * 16 + quad * 4] = *(const bf16x4*)t4;
            }
#pragma unroll
            for (int kb = 0; kb < 2; ++kb) {
                const bf16x8 ap = *(const bf16x8*)&pT[(w * 16 + l15) * 72 + kb * 32 + quad * 8];
#pragma unroll
                for (int cs = 0; cs < 4; ++cs) {
                    const bf16x8 bh2 = *(const bf16x8*)&hT[(cs * 16 + l15) * 72 + kb * 32 + quad * 8];
                    accA[cs] = __builtin_amdgcn_mfma_f32_16x16x32_bf16(ap, bh2, accA[cs], 0, 0, 0);
                }
            }
        }
        // ---- tile B (only when nc >= mtB) ----
        if (nc >= mtB) {
            const bool diag = (nc == mtB);
#pragma unroll
            for (int ns = 0; ns < 4; ++ns) {
                bf16x8 bg2 = {0, 0, 0, 0, 0, 0, 0, 0};
                if (quad == 0) bg2 = *(const bf16x8*)&gS[(ns * 16 + l15) * 8];
                f32x4 s = __builtin_amdgcn_mfma_f32_16x16x32_bf16(bg2, afB, cz, 0, 0, 0);
                const float4 zi4 = *(const float4*)&zS[ns * 16 + quad * 4];
                __hip_bfloat16 t4[4];
#pragma unroll
                for (int j = 0; j < 4; ++j) {
                    float p = __expf(s[j]) * ((const float*)&zi4)[j];
                    if (diag) {
                        const int n = n0c + ns * 16 + quad * 4 + j;
                        const int m = m0B + w * 16 + l15;
                        if (n < m) p = 0.f;
                    }
                    t4[j] = f2bf(p);
                }
                *(bf16x4*)&pT[(w * 16 + l15) * 72 + ns * 16 + quad * 4] = *(const bf16x4*)t4;
            }
#pragma unroll
            for (int kb = 0; kb < 2; ++kb) {
                const bf16x8 ap = *(const bf16x8*)&pT[(w * 16 + l15) * 72 + kb * 32 + quad * 8];
#pragma unroll
                for (int cs = 0; cs < 4; ++cs) {
                    const bf16x8 bh2 = *(const bf16x8*)&hT[(cs * 16 + l15) * 72 + kb * 32 + quad * 8];
                    accB[cs] = __builtin_amdgcn_mfma_f32_16x16x32_bf16(ap, bh2, accB[cs], 0, 0, 0);
                }
            }
        }
    }

    // ---- epilogue: both tiles' partial stores into plane hx ----
#pragma unroll
    for (int cs = 0; cs < 4; ++cs) {
        const int c = cs * 16 + l15;
        __hip_bfloat16 tA[4], tB[4];
#pragma unroll
        for (int j = 0; j < 4; ++j) { tA[j] = f2bf(accA[cs][j]); tB[j] = f2bf(accB[cs][j]); }
        const size_t base = ((size_t)((hx * NB + b) * 64 + c)) * HW;
        *(float2*)(opart + base + m0A + w * 16 + quad * 4) = *(const float2*)tA;
        *(float2*)(opart + base + m0B + w * 16 + quad * 4) = *(const float2*)tB;
    }
}

// ---------------------------------------------------------------------------
// Kernel 4: y = gamma * (sum of 8 partial planes) + x. 512 blocks.
// ---------------------------------------------------------------------------
__global__ __launch_bounds__(256) void k_epi(
    const __hip_bfloat16* __restrict__ opart, const float* __restrict__ x,
    const float* __restrict__ gamma, float* __restrict__ y)
{
    const int t = blockIdx.x * 256 + (int)threadIdx.x;
    const size_t e0 = (size_t)t * 8;
    const float ga = gamma[0];

    float acc[8] = {0, 0, 0, 0, 0, 0, 0, 0};
#pragma unroll
    for (int h = 0; h < 8; ++h) {
        const bf16x8 v = *(const bf16x8*)(opart + (size_t)h * (NB * CC * HW) + e0);
#pragma unroll
        for (int k = 0; k < 8; ++k) acc[k] += bf2f(v[k]);
    }
    const float4 x0 = *(const float4*)(x + e0);
    const float4 x1 = *(const float4*)(x + e0 + 4);
    float4 y0, y1;
    y0.x = ga * acc[0] + x0.x; y0.y = ga * acc[1] + x0.y;
    y0.z = ga * acc[2] + x0.z; y0.w = ga * acc[3] + x0.w;
    y1.x = ga * acc[4] + x1.x; y1.y = ga * acc[5] + x1.y;
    y1.z = ga * acc[6] + x1.z; y1.w = ga * acc[7] + x1.w;
    *(float4*)(y + e0) = y0;
    *(float4*)(y + e0 + 4) = y1;
}

extern "C" void kernel_launch(void* const* d_in, const int* in_sizes, int n_in,
                              void* d_out, int out_size, void* d_ws, size_t ws_size,
                              hipStream_t stream)
{
    const float* x     = (const float*)d_in[0];
    const float* Wf    = (const float*)d_in[1];
    const float* bfv   = (const float*)d_in[2];
    const float* Wg    = (const float*)d_in[3];
    const float* bgv   = (const float*)d_in[4];
    const float* Wh    = (const float*)d_in[5];
    const float* bhv   = (const float*)d_in[6];
    const float* gamma = (const float*)d_in[7];

    char* ws = (char*)d_ws;
    __hip_bfloat16* fb = (__hip_bfloat16*)(ws + OFF_F);
    __hip_bfloat16* gb = (__hip_bfloat16*)(ws + OFF_G);
    __hip_bfloat16* hb = (__hip_bfloat16*)(ws + OFF_H);
    float* zp          = (float*)(ws + OFF_ZP);
    __hip_bfloat16* opart = (__hip_bfloat16*)(ws + OFF_O);
    float* y = (float*)d_out;

    k_prep<<<dim3(128, 4), 256, 0, stream>>>(x, Wf, bfv, Wg, bgv, Wh, bhv, fb, gb, hb);
    k_z<<<dim3(64, 4, 2), 256, 0, stream>>>(fb, gb, zp);
    k_attn<<<dim3(8, 4, 32), 256, 0, stream>>>(fb, gb, hb, zp, opart);
    k_epi<<<512, 256, 0, stream>>>(opart, x, gamma, y);
}